// Round 1
// baseline (228.256 us; speedup 1.0000x reference)
//
#include <hip/hip_runtime.h>

// x: [B=64, N=4096, D=128] fp32; R: [B, N, 2, 2] fp32
// y[b,n,2c+i] = sum_j R[b,n,i,j] * x[b,n,2c+j]
//
// Pure streaming op (272.6 MB total traffic, zero reuse beyond a single
// instruction). Bottleneck analysis: the previous grid-stride version had an
// unknown trip count -> no unroll -> 1 outstanding x-load per lane ->
// latency-limited at ~4.4 TB/s. The launch divides the work exactly
// (8,388,608 f32x4 = 4 * 8192 * 256), so use a fixed 4-deep unroll that
// issues all 8 loads (4x x, 4x R) before the first waitcnt: 128 B in flight
// per lane. Nontemporal on x/out/R: none has cross-instruction reuse
// (each 16B R quad is consumed entirely by 32 lanes of one instruction).

typedef float f32x4 __attribute__((ext_vector_type(4)));

__device__ __forceinline__ f32x4 rot2(f32x4 r, f32x4 xv) {
    f32x4 y;
    y.x = r.x * xv.x + r.y * xv.y;  // R00*x0 + R01*x1
    y.y = r.z * xv.x + r.w * xv.y;  // R10*x0 + R11*x1
    y.z = r.x * xv.z + r.y * xv.w;  // R00*x2 + R01*x3
    y.w = r.z * xv.z + r.w * xv.w;  // R10*x2 + R11*x3
    return y;
}

// Exact-division fast path: each thread handles 4 f32x4 at stride S.
// No bounds checks, fixed trip count, all loads issued up front.
__global__ __launch_bounds__(256) void rotate2d_unroll4(
    const f32x4* __restrict__ x,
    const f32x4* __restrict__ R,    // one f32x4 per point: (R00,R01,R10,R11)
    f32x4* __restrict__ out,
    int S)                          // stride in f32x4 units = gridDim*blockDim
{
    int t = blockIdx.x * blockDim.x + threadIdx.x;

    // 4 x-loads in flight
    f32x4 x0 = __builtin_nontemporal_load(&x[t]);
    f32x4 x1 = __builtin_nontemporal_load(&x[t + S]);
    f32x4 x2 = __builtin_nontemporal_load(&x[t + 2 * S]);
    f32x4 x3 = __builtin_nontemporal_load(&x[t + 3 * S]);

    // 4 R-loads in flight (S is a multiple of 32, so (t+kS)>>5 = (t>>5)+k*(S>>5))
    int rb = t >> 5;
    int rs = S >> 5;
    f32x4 r0 = __builtin_nontemporal_load(&R[rb]);
    f32x4 r1 = __builtin_nontemporal_load(&R[rb + rs]);
    f32x4 r2 = __builtin_nontemporal_load(&R[rb + 2 * rs]);
    f32x4 r3 = __builtin_nontemporal_load(&R[rb + 3 * rs]);

    __builtin_nontemporal_store(rot2(r0, x0), &out[t]);
    __builtin_nontemporal_store(rot2(r1, x1), &out[t + S]);
    __builtin_nontemporal_store(rot2(r2, x2), &out[t + 2 * S]);
    __builtin_nontemporal_store(rot2(r3, x3), &out[t + 3 * S]);
}

// Fallback for sizes that don't divide exactly (kept from previous version).
__global__ __launch_bounds__(256) void rotate2d_generic(
    const f32x4* __restrict__ x,
    const f32x4* __restrict__ R,
    f32x4* __restrict__ out,
    int n4)
{
    int stride = blockDim.x * gridDim.x;
    for (int t = blockIdx.x * blockDim.x + threadIdx.x; t < n4; t += stride) {
        f32x4 xv = __builtin_nontemporal_load(&x[t]);
        f32x4 r  = R[t >> 5];
        __builtin_nontemporal_store(rot2(r, xv), &out[t]);
    }
}

extern "C" void kernel_launch(void* const* d_in, const int* in_sizes, int n_in,
                              void* d_out, int out_size, void* d_ws, size_t ws_size,
                              hipStream_t stream) {
    const f32x4* x = (const f32x4*)d_in[0];
    const f32x4* R = (const f32x4*)d_in[1];
    f32x4* out = (f32x4*)d_out;

    int n4 = in_sizes[0] / 4;       // 64*4096*128 / 4 = 8,388,608 f32x4
    int block = 256;
    int grid = 8192;
    int S = grid * block;           // 2,097,152

    if (n4 == 4 * S) {
        // Exact: 4 chunks per thread, fully unrolled, 8 loads in flight/lane.
        rotate2d_unroll4<<<grid, block, 0, stream>>>(x, R, out, S);
    } else {
        rotate2d_generic<<<grid, block, 0, stream>>>(x, R, out, n4);
    }
}